// Round 9
// baseline (400.930 us; speedup 1.0000x reference)
//
#include <hip/hip_runtime.h>
#include <hip/hip_bf16.h>
#include <math.h>

// Problem constants (match reference)
#define BB  32
#define SS  4096
#define VV  256
#define DD  256
#define CC  2
#define WIN 64
#define NW  64   // SS/WIN

typedef unsigned short ushort_t;
typedef unsigned int   uint_t;
typedef __attribute__((ext_vector_type(8))) short short8;    // 8 bf16 (4 VGPRs)
typedef __attribute__((ext_vector_type(4))) float f32x4;

// Workspace layout (byte offsets).
#define WS_ATHI_B 0u          // ushort Athi[64][64]   8192  (A-op layout: [t][s])
#define WS_ATLO_B 8192u       // ushort Atlo[64][64]   8192
#define WS_GPK_B  16384u      // uint   gpk[256][256]  262144 (hi<<16 | lo per elem)
#define WS_W2HI_B 278528u     // ushort W2hi[256][256] 131072
#define WS_W2LO_B 409600u     // ushort W2lo[256][256] 131072

#define HP 264    // H2 plane row stride in shorts (256 + 8 pad)

__device__ __forceinline__ float fast_tanh(float v) {
  float e = __expf(2.0f * v);
  return 1.0f - __fdividef(2.0f, e + 1.0f);
}

// Truncation-based bf16 split: v ~= hi + lo with |err| <= 2^-17 * |v|.
__device__ __forceinline__ uint_t split_pack(float v) {
  uint_t b  = __float_as_uint(v);
  uint_t hi = b & 0xffff0000u;
  float  r  = v - __uint_as_float(hi);
  uint_t lo = __float_as_uint(r) >> 16;
  return hi | lo;
}

// Pack hi/lo halves of two packed u32 into bf16 pair dwords via v_perm.
__device__ __forceinline__ uint_t perm_hi(uint_t p0, uint_t p1) {
  return __builtin_amdgcn_perm(p1, p0, 0x07060302u);
}
__device__ __forceinline__ uint_t perm_lo(uint_t p0, uint_t p1) {
  return __builtin_amdgcn_perm(p1, p0, 0x05040100u);
}

union u4s8 { uint_t u[4]; short8 v; };

// Async global->LDS DMA, 16B per lane: lane i -> ldsbase + 16*i (wave-uniform
// LDS base, per-lane global address). m97 pattern.
__device__ __forceinline__ void async_lds16(const uint_t* g, uint_t* l) {
  __builtin_amdgcn_global_load_lds(
      (const __attribute__((address_space(1))) uint_t*)g,
      (__attribute__((address_space(3))) uint_t*)l, 16, 0, 0);
}

// ---------------------------------------------------------------------------
// Prep grid (1090 blocks):
//  blk 0          : attention matrix -> split bf16 planes Athi/Atlo ([t][s])
//  blk 1          : out[b][c] = bc[c]  (main atomically accumulates into out)
//  blk 2..1025    : g = emb @ W1^T (coalesced W1 reads, LDS partial reduce)
//  blk 1026..1089 : W2 -> split planes W2hi/W2lo, 4 c-rows per block
// ---------------------------------------------------------------------------
__global__ __launch_bounds__(256) void prep_kernel(
    const float* __restrict__ emb, const float* __restrict__ W1,
    const float* __restrict__ W2,  const float* __restrict__ bc,
    float* __restrict__ out, char* __restrict__ ws)
{
  const int blk = blockIdx.x;
  const int tid = threadIdx.x;
  ushort_t* Athi = (ushort_t*)(ws + WS_ATHI_B);
  ushort_t* Atlo = (ushort_t*)(ws + WS_ATLO_B);
  uint_t*   gpk  = (uint_t*)  (ws + WS_GPK_B);
  ushort_t* W2hi = (ushort_t*)(ws + WS_W2HI_B);
  ushort_t* W2lo = (ushort_t*)(ws + WS_W2LO_B);

  if (blk == 0) {
    if (tid < WIN) {
      const int s = tid;
      const float omega = 60.0f * 2.0f * 3.14159265358979323846f / 4095.0f;
      float row[WIN];
      float sum = 0.0f;
      for (int t = 0; t < WIN; ++t) {
        float e = expf(cosf(omega * (float)(s - t)));
        row[t] = e;
        sum += e;
      }
      const float inv = 1.0f / sum;
      for (int t = 0; t < WIN; ++t) {
        uint_t pk = split_pack(row[t] * inv);
        Athi[t * WIN + s] = (ushort_t)(pk >> 16);
        Atlo[t * WIN + s] = (ushort_t)(pk & 0xffffu);
      }
    }
  } else if (blk == 1) {
    if (tid < BB * CC) out[tid] = bc[tid & 1];
  } else if (blk < 1026) {
    const int gv = blk - 2;            // 0..1023
    const int d0 = (gv & 15) * 16;     // 16 d-columns
    const int v0 = (gv >> 4) * 4;      // 4 v-rows
    __shared__ float er[4 * DD];       // 4 KB
    __shared__ float ps[4][16][17];    // padded partials
    *(float4*)(er + tid * 4) = *(const float4*)(emb + v0 * DD + tid * 4);
    __syncthreads();
    const int kq = tid & 15;           // k-strip: [16kq, 16kq+16)
    const int dl = tid >> 4;           // 0..15
    const int d  = d0 + dl;
    float4 wv[4];
    #pragma unroll
    for (int j = 0; j < 4; ++j)
      wv[j] = *(const float4*)(W1 + d * DD + 16 * kq + 4 * j);  // coalesced
    #pragma unroll
    for (int v = 0; v < 4; ++v) {
      float a = 0.0f;
      #pragma unroll
      for (int j = 0; j < 4; ++j) {
        float4 e = *(const float4*)(er + v * DD + 16 * kq + 4 * j);
        a += e.x * wv[j].x + e.y * wv[j].y + e.z * wv[j].z + e.w * wv[j].w;
      }
      ps[v][dl][kq] = a;
    }
    __syncthreads();
    if (tid < 64) {
      const int v = tid >> 4, dr = tid & 15;
      float s = 0.0f;
      #pragma unroll
      for (int k = 0; k < 16; ++k) s += ps[v][dr][k];
      gpk[(v0 + v) * DD + d0 + dr] = split_pack(s);
    }
  } else {
    const int c0 = (blk - 1026) * 4;
    #pragma unroll
    for (int i = 0; i < 4; ++i) {
      const int c = c0 + i;
      uint_t pk = split_pack(W2[c * DD + tid]);
      W2hi[c * DD + tid] = (ushort_t)(pk >> 16);
      W2lo[c * DD + tid] = (ushort_t)(pk & 0xffffu);
    }
  }
}

// ---------------------------------------------------------------------------
// Main fused kernel: one block (512 thr, 8 waves) per (batch b, window n).
//  P1: gather via global_load_lds DMA: wave w stages rows 8w..8w+7 of the
//      token-gathered g matrix into LDS G[64][256] (1 KB per instruction,
//      scalar token index, zero VGPR in flight). Per-wave 16B-chunk rotation
//      rot=2*(w&3): read-side bank occupancy = exactly 2 lanes/bank (free).
//  P2: attention MFMA; B-frags = 8 imm-offset ds_read_b32 + v_perm unpack.
//  P3: tanh(+b1), split -> Hhi/Hlo planes [64][264] (read-conflict-free).
//  P4: matmul2 MFMA, W2 planes double-buffered from L2, A-frags direct b128.
//  P5: tanh(+b2), fold into Wc (head is linear in pooled sums), butterfly
//      reduce, 2 atomicAdds per wave straight into out.
// ---------------------------------------------------------------------------
__global__ __launch_bounds__(512, 4) void main_kernel(
    const int*      __restrict__ x,    const uint_t* __restrict__ gpk,
    const ushort_t* __restrict__ Athi, const ushort_t* __restrict__ Atlo,
    const float*    __restrict__ b1,
    const ushort_t* __restrict__ W2hi, const ushort_t* __restrict__ W2lo,
    const float*    __restrict__ b2,   const float* __restrict__ Wc,
    float* __restrict__ out)
{
  __shared__ char ldsbuf[67584];   // union: G (65536) / Hhi+Hlo (67584)
  uint_t* G = (uint_t*)ldsbuf;                       // [64][256] packed
  ushort_t (*Hhi)[HP] = (ushort_t(*)[HP])(ldsbuf);
  ushort_t (*Hlo)[HP] = (ushort_t(*)[HP])(ldsbuf + 33792);

  const int tid  = threadIdx.x;
  const int lane = tid & 63;
  const int w    = tid >> 6;       // 0..7
  const int quad = lane >> 4;
  const int l16  = lane & 15;
  const int b = blockIdx.x >> 6;
  const int n = blockIdx.x & 63;

  const int dbase = 32 * w;        // this wave's d-slice (P2) == c-slice (P4)
  const int cbase = dbase;

  // --- P1: DMA-stage gathered g rows into G with chunk rotation ---
  const int gchunk = ((lane + 2 * (w & 3)) & 63) << 2;   // dword offset in row
  const int xoff = b * SS + n * WIN + 8 * w;
  #pragma unroll
  for (int i = 0; i < 8; ++i) {
    const int tok = x[xoff + i];                         // wave-uniform
    async_lds16(gpk + tok * DD + gchunk, G + (8 * w + i) * DD);
  }

  float b1v[2], b2v[2];
  #pragma unroll
  for (int nt = 0; nt < 2; ++nt) {
    b1v[nt] = b1[dbase + 16 * nt + l16];
    b2v[nt] = b2[cbase + 16 * nt + l16];
  }

  __syncthreads();   // DMA drained (compiler waits vmcnt before barrier)

  // --- P2: attention MFMA, B-frags from G ---
  f32x4 acc1[4][2];
  #pragma unroll
  for (int mt = 0; mt < 4; ++mt)
    #pragma unroll
    for (int nt = 0; nt < 2; ++nt) acc1[mt][nt] = (f32x4)0.0f;

  #pragma unroll
  for (int k0 = 0; k0 < 2; ++k0) {
    const int sl = k0 * 32 + quad * 8;
    short8 bh[2], bl[2];
    #pragma unroll
    for (int nt = 0; nt < 2; ++nt) {
      const int d = dbase + 16 * nt + l16;
      // rotated position of element d in its row (rotation = 2*quad chunks)
      const int ridx = ((((d >> 2) - 2 * quad) & 63) << 2) + (l16 & 3);
      const uint_t* bp = G + sl * DD + ridx;
      uint_t q[8];
      #pragma unroll
      for (int j = 0; j < 8; ++j) q[j] = bp[j * DD];     // ds_read_b32, 2-way
      u4s8 h, l;
      #pragma unroll
      for (int p = 0; p < 4; ++p) {
        h.u[p] = perm_hi(q[2 * p], q[2 * p + 1]);
        l.u[p] = perm_lo(q[2 * p], q[2 * p + 1]);
      }
      bh[nt] = h.v;
      bl[nt] = l.v;
    }
    #pragma unroll
    for (int mt = 0; mt < 4; ++mt) {
      const int t = mt * 16 + l16;
      short8 ah = *(const short8*)(Athi + t * WIN + sl);   // L1-resident
      short8 al = *(const short8*)(Atlo + t * WIN + sl);
      #pragma unroll
      for (int nt = 0; nt < 2; ++nt) {
        acc1[mt][nt] = __builtin_amdgcn_mfma_f32_16x16x32_bf16(ah, bh[nt], acc1[mt][nt], 0, 0, 0);
        acc1[mt][nt] = __builtin_amdgcn_mfma_f32_16x16x32_bf16(ah, bl[nt], acc1[mt][nt], 0, 0, 0);
        acc1[mt][nt] = __builtin_amdgcn_mfma_f32_16x16x32_bf16(al, bh[nt], acc1[mt][nt], 0, 0, 0);
      }
    }
  }
  __syncthreads();   // G fully consumed; LDS becomes H2 planes

  // --- P3: tanh(+b1), split, store to hi/lo planes ---
  #pragma unroll
  for (int nt = 0; nt < 2; ++nt) {
    const int d = dbase + 16 * nt + l16;
    #pragma unroll
    for (int mt = 0; mt < 4; ++mt)
      #pragma unroll
      for (int r = 0; r < 4; ++r) {
        const int t = mt * 16 + quad * 4 + r;
        float h = fast_tanh(acc1[mt][nt][r] + b1v[nt]);
        uint_t pk = split_pack(h);
        Hhi[t][d] = (ushort_t)(pk >> 16);
        Hlo[t][d] = (ushort_t)(pk & 0xffffu);
      }
  }
  __syncthreads();

  // --- P4: matmul2 MFMA, W2 double-buffered, A-frags direct b128 ---
  f32x4 acc2[4][2];
  #pragma unroll
  for (int mt = 0; mt < 4; ++mt)
    #pragma unroll
    for (int nt = 0; nt < 2; ++nt) acc2[mt][nt] = (f32x4)0.0f;

  short8 wh[2][2], wl[2][2];
  {
    const int dsl0 = quad * 8;
    #pragma unroll
    for (int nt = 0; nt < 2; ++nt) {
      const int c = cbase + 16 * nt + l16;
      wh[0][nt] = *(const short8*)(W2hi + c * DD + dsl0);
      wl[0][nt] = *(const short8*)(W2lo + c * DD + dsl0);
    }
  }

  #pragma unroll 2
  for (int k0 = 0; k0 < 8; ++k0) {
    const int cur = k0 & 1, nxt = cur ^ 1;
    const int dsl = k0 * 32 + quad * 8;
    if (k0 < 7) {
      const int dsln = dsl + 32;
      #pragma unroll
      for (int nt = 0; nt < 2; ++nt) {
        const int c = cbase + 16 * nt + l16;
        wh[nxt][nt] = *(const short8*)(W2hi + c * DD + dsln);   // prefetch k0+1
        wl[nxt][nt] = *(const short8*)(W2lo + c * DD + dsln);
      }
    }
    #pragma unroll
    for (int mt = 0; mt < 4; ++mt) {
      const int t = mt * 16 + l16;
      short8 ah = *(const short8*)(&Hhi[t][dsl]);   // ds_read_b128, clean
      short8 al = *(const short8*)(&Hlo[t][dsl]);
      #pragma unroll
      for (int nt = 0; nt < 2; ++nt) {
        acc2[mt][nt] = __builtin_amdgcn_mfma_f32_16x16x32_bf16(ah, wh[cur][nt], acc2[mt][nt], 0, 0, 0);
        acc2[mt][nt] = __builtin_amdgcn_mfma_f32_16x16x32_bf16(ah, wl[cur][nt], acc2[mt][nt], 0, 0, 0);
        acc2[mt][nt] = __builtin_amdgcn_mfma_f32_16x16x32_bf16(al, wh[cur][nt], acc2[mt][nt], 0, 0, 0);
      }
    }
  }

  // --- P5: tanh(+b2), token-sum, fold into Wc, atomicAdd into out ---
  float pacc[2];
  #pragma unroll
  for (int nt = 0; nt < 2; ++nt) {
    float p = 0.0f;
    #pragma unroll
    for (int mt = 0; mt < 4; ++mt)
      #pragma unroll
      for (int r = 0; r < 4; ++r)
        p += fast_tanh(acc2[mt][nt][r] + b2v[nt]);
    p += __shfl_xor(p, 16, 64);   // sum across quads (different t only)
    p += __shfl_xor(p, 32, 64);
    pacc[nt] = p;                 // all lanes: token-sum for c = cbase+16nt+l16
  }
  // head is linear in pooled sums: out[b][cls] += sum_c pacc[c]*Wc[cls][c]/SS
  float s0 = pacc[0] * Wc[cbase + l16]      + pacc[1] * Wc[cbase + 16 + l16];
  float s1 = pacc[0] * Wc[DD + cbase + l16] + pacc[1] * Wc[DD + cbase + 16 + l16];
  #pragma unroll
  for (int off = 1; off < 16; off <<= 1) {   // sum over l16 (quads identical)
    s0 += __shfl_xor(s0, off, 64);
    s1 += __shfl_xor(s1, off, 64);
  }
  if (lane == 0) {
    atomicAdd(&out[b * CC + 0], s0 * (1.0f / SS));
    atomicAdd(&out[b * CC + 1], s1 * (1.0f / SS));
  }
}

extern "C" void kernel_launch(void* const* d_in, const int* in_sizes, int n_in,
                              void* d_out, int out_size, void* d_ws, size_t ws_size,
                              hipStream_t stream) {
  const int*   x   = (const int*)  d_in[0];
  const float* emb = (const float*)d_in[1];
  const float* W1  = (const float*)d_in[2];
  const float* b1  = (const float*)d_in[3];
  const float* W2  = (const float*)d_in[4];
  const float* b2  = (const float*)d_in[5];
  const float* Wc  = (const float*)d_in[6];
  const float* bc  = (const float*)d_in[7];
  float* out = (float*)d_out;
  char*  ws  = (char*)d_ws;

  prep_kernel<<<1090, 256, 0, stream>>>(emb, W1, W2, bc, out, ws);
  main_kernel<<<BB * NW, 512, 0, stream>>>(
      x,
      (const uint_t*)  (ws + WS_GPK_B),
      (const ushort_t*)(ws + WS_ATHI_B), (const ushort_t*)(ws + WS_ATLO_B),
      b1,
      (const ushort_t*)(ws + WS_W2HI_B), (const ushort_t*)(ws + WS_W2LO_B),
      b2, Wc, out);
}

// Round 10
// 191.770 us; speedup vs baseline: 2.0907x; 2.0907x over previous
//
#include <hip/hip_runtime.h>
#include <hip/hip_bf16.h>
#include <math.h>

// Problem constants (match reference)
#define BB  32
#define SS  4096
#define VV  256
#define DD  256
#define CC  2
#define WIN 64
#define NW  64   // SS/WIN
#define WPB 8    // windows per block (pipelined)

typedef unsigned short ushort_t;
typedef unsigned int   uint_t;
typedef __attribute__((ext_vector_type(8))) short short8;    // 8 bf16 (4 VGPRs)
typedef __attribute__((ext_vector_type(4))) float f32x4;

// Workspace layout (byte offsets).
#define WS_ATHI_B 0u          // ushort Athi[64][64]   8192  (A-op layout: [t][s])
#define WS_ATLO_B 8192u       // ushort Atlo[64][64]   8192
#define WS_GPK_B  16384u      // uint   gpk[256][256]  262144 (hi<<16 | lo per elem)
#define WS_W2HI_B 278528u     // ushort W2hi[256][256] 131072
#define WS_W2LO_B 409600u     // ushort W2lo[256][256] 131072

#define HP 264        // H2 plane row stride in shorts (256 + 8 pad, 16B-aligned rows)
#define LDSBUF 67584  // one window's Hhi+Hlo (2 * 64 * 264 * 2B)

__device__ __forceinline__ float fast_tanh(float v) {
  float e = __expf(2.0f * v);
  return 1.0f - __fdividef(2.0f, e + 1.0f);
}

// Truncation-based bf16 split: v ~= hi + lo with |err| <= 2^-17 * |v|.
__device__ __forceinline__ uint_t split_pack(float v) {
  uint_t b  = __float_as_uint(v);
  uint_t hi = b & 0xffff0000u;
  float  r  = v - __uint_as_float(hi);
  uint_t lo = __float_as_uint(r) >> 16;
  return hi | lo;
}

// Pack hi/lo halves of two packed u32 into bf16 pair dwords via v_perm.
__device__ __forceinline__ uint_t perm_hi(uint_t p0, uint_t p1) {
  return __builtin_amdgcn_perm(p1, p0, 0x07060302u);
}
__device__ __forceinline__ uint_t perm_lo(uint_t p0, uint_t p1) {
  return __builtin_amdgcn_perm(p1, p0, 0x05040100u);
}

union u4s8 { uint_t u[4]; short8 v; };

// ---------------------------------------------------------------------------
// Prep grid (1090 blocks):
//  blk 0          : attention matrix -> split bf16 planes Athi/Atlo ([t][s])
//  blk 1          : out[b][c] = bc[c]  (main atomically accumulates into out)
//  blk 2..1025    : g = emb @ W1^T (coalesced W1 reads, LDS partial reduce)
//  blk 1026..1089 : W2 -> split planes W2hi/W2lo, 4 c-rows per block
// ---------------------------------------------------------------------------
__global__ __launch_bounds__(256) void prep_kernel(
    const float* __restrict__ emb, const float* __restrict__ W1,
    const float* __restrict__ W2,  const float* __restrict__ bc,
    float* __restrict__ out, char* __restrict__ ws)
{
  const int blk = blockIdx.x;
  const int tid = threadIdx.x;
  ushort_t* Athi = (ushort_t*)(ws + WS_ATHI_B);
  ushort_t* Atlo = (ushort_t*)(ws + WS_ATLO_B);
  uint_t*   gpk  = (uint_t*)  (ws + WS_GPK_B);
  ushort_t* W2hi = (ushort_t*)(ws + WS_W2HI_B);
  ushort_t* W2lo = (ushort_t*)(ws + WS_W2LO_B);

  if (blk == 0) {
    if (tid < WIN) {
      const int s = tid;
      const float omega = 60.0f * 2.0f * 3.14159265358979323846f / 4095.0f;
      float row[WIN];
      float sum = 0.0f;
      for (int t = 0; t < WIN; ++t) {
        float e = expf(cosf(omega * (float)(s - t)));
        row[t] = e;
        sum += e;
      }
      const float inv = 1.0f / sum;
      for (int t = 0; t < WIN; ++t) {
        uint_t pk = split_pack(row[t] * inv);
        Athi[t * WIN + s] = (ushort_t)(pk >> 16);
        Atlo[t * WIN + s] = (ushort_t)(pk & 0xffffu);
      }
    }
  } else if (blk == 1) {
    if (tid < BB * CC) out[tid] = bc[tid & 1];
  } else if (blk < 1026) {
    const int gv = blk - 2;            // 0..1023
    const int d0 = (gv & 15) * 16;     // 16 d-columns
    const int v0 = (gv >> 4) * 4;      // 4 v-rows
    __shared__ float er[4 * DD];       // 4 KB
    __shared__ float ps[4][16][17];    // padded partials
    *(float4*)(er + tid * 4) = *(const float4*)(emb + v0 * DD + tid * 4);
    __syncthreads();
    const int kq = tid & 15;           // k-strip: [16kq, 16kq+16)
    const int dl = tid >> 4;           // 0..15
    const int d  = d0 + dl;
    float4 wv[4];
    #pragma unroll
    for (int j = 0; j < 4; ++j)
      wv[j] = *(const float4*)(W1 + d * DD + 16 * kq + 4 * j);  // coalesced
    #pragma unroll
    for (int v = 0; v < 4; ++v) {
      float a = 0.0f;
      #pragma unroll
      for (int j = 0; j < 4; ++j) {
        float4 e = *(const float4*)(er + v * DD + 16 * kq + 4 * j);
        a += e.x * wv[j].x + e.y * wv[j].y + e.z * wv[j].z + e.w * wv[j].w;
      }
      ps[v][dl][kq] = a;
    }
    __syncthreads();
    if (tid < 64) {
      const int v = tid >> 4, dr = tid & 15;
      float s = 0.0f;
      #pragma unroll
      for (int k = 0; k < 16; ++k) s += ps[v][dr][k];
      gpk[(v0 + v) * DD + d0 + dr] = split_pack(s);
    }
  } else {
    const int c0 = (blk - 1026) * 4;
    #pragma unroll
    for (int i = 0; i < 4; ++i) {
      const int c = c0 + i;
      uint_t pk = split_pack(W2[c * DD + tid]);
      W2hi[c * DD + tid] = (ushort_t)(pk >> 16);
      W2lo[c * DD + tid] = (ushort_t)(pk & 0xffffu);
    }
  }
}

// ---------------------------------------------------------------------------
// Main kernel: 256 blocks (1/CU), 512 thr, WPB=8 windows each, producer/
// consumer wave specialization with double-buffered H2 (2 x 67.5 KB LDS).
//  Waves 0-3 (producers), wave p owns d in [64p, 64p+64):
//    gather gpk rows (register gather, per-k0 batches) -> attention MFMA
//    (A = At split planes, L1) -> tanh(+b1) -> split -> Hhi/Hlo[buf it&1].
//  Waves 4-7 (consumers), wave c' owns c in [64c', 64c'+64), window it-1:
//    matmul2 MFMA (A-frags: direct ds_read_b128 from buf (it-1)&1; B: W2
//    split planes from L1/L2) -> tanh(+b2) -> pacc accumulate.
//  One barrier per iteration. Wave->SIMD round-robin puts one producer and
//  one consumer on each SIMD: gather latency hides under consumer MFMA.
//  Epilogue (consumers): fold pacc into Wc (head is linear), butterfly over
//  l16, 2 atomicAdds per wave into out.
// ---------------------------------------------------------------------------
__global__ __launch_bounds__(512, 2) void main_kernel(
    const int*      __restrict__ x,    const uint_t* __restrict__ gpk,
    const ushort_t* __restrict__ Athi, const ushort_t* __restrict__ Atlo,
    const float*    __restrict__ b1,
    const ushort_t* __restrict__ W2hi, const ushort_t* __restrict__ W2lo,
    const float*    __restrict__ b2,   const float* __restrict__ Wc,
    float* __restrict__ out)
{
  __shared__ char lds[2 * LDSBUF];   // 135168 B -> 1 block/CU

  const int tid  = threadIdx.x;
  const int lane = tid & 63;
  const int w    = tid >> 6;       // 0..7
  const int quad = lane >> 4;
  const int l16  = lane & 15;
  const int win0 = blockIdx.x * WPB;      // 8 windows, same b (8 | 64)
  const int b    = win0 >> 6;
  const bool producer = (w < 4);
  const int rid   = w & 3;
  const int dbase = 64 * rid;      // producer d-range / consumer c-range

  float bias[4];
  #pragma unroll
  for (int nt = 0; nt < 4; ++nt)
    bias[nt] = producer ? b1[dbase + 16 * nt + l16] : b2[dbase + 16 * nt + l16];

  float pacc[4] = {0.0f, 0.0f, 0.0f, 0.0f};

  #pragma unroll 1
  for (int it = 0; it <= WPB; ++it) {
    if (producer) {
      if (it < WPB) {
        char* base = lds + (it & 1) * LDSBUF;
        ushort_t (*Hhi)[HP] = (ushort_t(*)[HP])base;
        ushort_t (*Hlo)[HP] = (ushort_t(*)[HP])(base + LDSBUF / 2);
        const int n = (win0 + it) & 63;
        const int xv = x[b * SS + n * WIN + lane];

        f32x4 acc1[4][4];
        #pragma unroll
        for (int mt = 0; mt < 4; ++mt)
          #pragma unroll
          for (int nt = 0; nt < 4; ++nt) acc1[mt][nt] = (f32x4)0.0f;

        #pragma unroll
        for (int k0 = 0; k0 < 2; ++k0) {
          const int sl = k0 * 32 + quad * 8;
          int xs[8];
          #pragma unroll
          for (int j = 0; j < 8; ++j) xs[j] = __shfl(xv, sl + j, 64);
          uint_t q[4][8];                      // 32-reg gather batch
          #pragma unroll
          for (int nt = 0; nt < 4; ++nt) {
            const int d = dbase + 16 * nt + l16;
            #pragma unroll
            for (int j = 0; j < 8; ++j) q[nt][j] = gpk[xs[j] * DD + d];
          }
          short8 bh[4], bl[4];
          #pragma unroll
          for (int nt = 0; nt < 4; ++nt) {
            u4s8 h, l;
            #pragma unroll
            for (int p = 0; p < 4; ++p) {
              h.u[p] = perm_hi(q[nt][2 * p], q[nt][2 * p + 1]);
              l.u[p] = perm_lo(q[nt][2 * p], q[nt][2 * p + 1]);
            }
            bh[nt] = h.v;
            bl[nt] = l.v;
          }
          #pragma unroll
          for (int mt = 0; mt < 4; ++mt) {
            const int t = mt * 16 + l16;
            short8 ah = *(const short8*)(Athi + t * WIN + sl);   // L1
            short8 al = *(const short8*)(Atlo + t * WIN + sl);
            #pragma unroll
            for (int nt = 0; nt < 4; ++nt) {
              acc1[mt][nt] = __builtin_amdgcn_mfma_f32_16x16x32_bf16(ah, bh[nt], acc1[mt][nt], 0, 0, 0);
              acc1[mt][nt] = __builtin_amdgcn_mfma_f32_16x16x32_bf16(ah, bl[nt], acc1[mt][nt], 0, 0, 0);
              acc1[mt][nt] = __builtin_amdgcn_mfma_f32_16x16x32_bf16(al, bh[nt], acc1[mt][nt], 0, 0, 0);
            }
          }
        }

        // tanh(+b1), split, store planes (b16 writes, ~2 lanes/bank)
        #pragma unroll
        for (int nt = 0; nt < 4; ++nt) {
          const int d = dbase + 16 * nt + l16;
          #pragma unroll
          for (int mt = 0; mt < 4; ++mt)
            #pragma unroll
            for (int r = 0; r < 4; ++r) {
              const int t = mt * 16 + quad * 4 + r;
              float h = fast_tanh(acc1[mt][nt][r] + bias[nt]);
              uint_t pk = split_pack(h);
              Hhi[t][d] = (ushort_t)(pk >> 16);
              Hlo[t][d] = (ushort_t)(pk & 0xffffu);
            }
        }
      }
    } else {
      if (it > 0) {
        char* base = lds + ((it - 1) & 1) * LDSBUF;
        ushort_t (*Hhi)[HP] = (ushort_t(*)[HP])base;
        ushort_t (*Hlo)[HP] = (ushort_t(*)[HP])(base + LDSBUF / 2);

        f32x4 acc2[4][4];
        #pragma unroll
        for (int mt = 0; mt < 4; ++mt)
          #pragma unroll
          for (int nt = 0; nt < 4; ++nt) acc2[mt][nt] = (f32x4)0.0f;

        #pragma unroll 1
        for (int k0 = 0; k0 < 8; ++k0) {
          const int dsl = k0 * 32 + quad * 8;
          short8 wh[4], wl[4];
          #pragma unroll
          for (int nt = 0; nt < 4; ++nt) {
            const int c = dbase + 16 * nt + l16;
            wh[nt] = *(const short8*)(W2hi + c * DD + dsl);   // L1/L2 resident
            wl[nt] = *(const short8*)(W2lo + c * DD + dsl);
          }
          #pragma unroll
          for (int mt = 0; mt < 4; ++mt) {
            const int t = mt * 16 + l16;
            short8 ah = *(const short8*)(&Hhi[t][dsl]);   // ds_read_b128, clean
            short8 al = *(const short8*)(&Hlo[t][dsl]);
            #pragma unroll
            for (int nt = 0; nt < 4; ++nt) {
              acc2[mt][nt] = __builtin_amdgcn_mfma_f32_16x16x32_bf16(ah, wh[nt], acc2[mt][nt], 0, 0, 0);
              acc2[mt][nt] = __builtin_amdgcn_mfma_f32_16x16x32_bf16(ah, wl[nt], acc2[mt][nt], 0, 0, 0);
              acc2[mt][nt] = __builtin_amdgcn_mfma_f32_16x16x32_bf16(al, wh[nt], acc2[mt][nt], 0, 0, 0);
            }
          }
        }

        // tanh(+b2), token-sum across quads, accumulate into pacc
        #pragma unroll
        for (int nt = 0; nt < 4; ++nt) {
          float p = 0.0f;
          #pragma unroll
          for (int mt = 0; mt < 4; ++mt)
            #pragma unroll
            for (int r = 0; r < 4; ++r)
              p += fast_tanh(acc2[mt][nt][r] + bias[nt]);
          p += __shfl_xor(p, 16, 64);
          p += __shfl_xor(p, 32, 64);
          pacc[nt] += p;
        }
      }
    }
    __syncthreads();
  }

  // Consumer epilogue: head is linear in pooled sums.
  if (!producer) {
    float s0 = 0.0f, s1 = 0.0f;
    #pragma unroll
    for (int nt = 0; nt < 4; ++nt) {
      const int c = dbase + 16 * nt + l16;
      s0 += pacc[nt] * Wc[c];
      s1 += pacc[nt] * Wc[DD + c];
    }
    #pragma unroll
    for (int off = 1; off < 16; off <<= 1) {   // reduce over l16 (quads identical)
      s0 += __shfl_xor(s0, off, 64);
      s1 += __shfl_xor(s1, off, 64);
    }
    if (lane == 0) {
      atomicAdd(&out[b * CC + 0], s0 * (1.0f / SS));
      atomicAdd(&out[b * CC + 1], s1 * (1.0f / SS));
    }
  }
}

extern "C" void kernel_launch(void* const* d_in, const int* in_sizes, int n_in,
                              void* d_out, int out_size, void* d_ws, size_t ws_size,
                              hipStream_t stream) {
  const int*   x   = (const int*)  d_in[0];
  const float* emb = (const float*)d_in[1];
  const float* W1  = (const float*)d_in[2];
  const float* b1  = (const float*)d_in[3];
  const float* W2  = (const float*)d_in[4];
  const float* b2  = (const float*)d_in[5];
  const float* Wc  = (const float*)d_in[6];
  const float* bc  = (const float*)d_in[7];
  float* out = (float*)d_out;
  char*  ws  = (char*)d_ws;

  prep_kernel<<<1090, 256, 0, stream>>>(emb, W1, W2, bc, out, ws);
  main_kernel<<<(BB * NW) / WPB, 512, 0, stream>>>(
      x,
      (const uint_t*)  (ws + WS_GPK_B),
      (const ushort_t*)(ws + WS_ATHI_B), (const ushort_t*)(ws + WS_ATLO_B),
      b1,
      (const ushort_t*)(ws + WS_W2HI_B), (const ushort_t*)(ws + WS_W2LO_B),
      b2, Wc, out);
}